// Round 5
// baseline (1081.884 us; speedup 1.0000x reference)
//
#include <hip/hip_runtime.h>
#include <stdint.h>

#define TT 1024
#define DX 32
#define DZ 64
#define DY 256
#define ALPHA 0.125f

typedef __attribute__((ext_vector_type(8))) short bf16x8;
typedef __attribute__((ext_vector_type(4))) float f32x4;

union Frag8 { bf16x8 v; uint32_t u[4]; };

// dword = [trunc_bf16(b) : trunc_bf16(a)]  (a in low 16 bits)
__device__ __forceinline__ uint32_t pk_hi16(float a, float b) {
    return __builtin_amdgcn_perm(__float_as_uint(b), __float_as_uint(a), 0x07060302u);
}
__device__ __forceinline__ float trunc_bf16_f32(float a) {
    return __uint_as_float(__float_as_uint(a) & 0xffff0000u);
}
// Truncation split of 8 consecutive floats into hi/lo bf16x8 frags (lo exact residual, then truncated).
__device__ __forceinline__ void split8(const float* p, bf16x8& hi, bf16x8& lo) {
    Frag8 H, L;
#pragma unroll
    for (int j = 0; j < 4; ++j) {
        float a = p[2 * j], b = p[2 * j + 1];
        H.u[j] = pk_hi16(a, b);
        float ra = a - trunc_bf16_f32(a);
        float rb = b - trunc_bf16_f32(b);
        L.u[j] = pk_hi16(ra, rb);
    }
    hi = H.v; lo = L.v;
}

// LDS layout (shorts, inside one flat dword array — no TBAA ambiguity):
//   zf_hi[2][16][72] @ 0      zf_lo[2][16][72] @ 2304
//   hd_hi[16][264]   @ 4608   hd_lo[16][264]   @ 8832
#define ZF_PAR 1152   // 16*72
#define ZF_ROW 72
#define HD_ROW 264
#define LDS_DWORDS 6528  // 13056 shorts

// 32 blocks (batch groups of 16 = MFMA N dim), 512 threads (8 waves).
// GEMM1: wave w computes hidden rows [32w, 32w+32) (2 M-tiles), K=64, 3-term
//        split -> 12 MFMA/wave.  Epilogue: relu + hi/lo split -> hd LDS.
// GEMM2: waves 0-3 only; wave w computes z-tile m2=w over FULL K=256
//        (8 k-frags x 3 terms = 24 MFMA, two interleaved 12-chains), then does
//        the update + teacher forcing + zf write itself (no partial exchange).
// zf is ping-ponged by t-parity; 2 barriers/step. All LDS zero-initialized at
// start so results cannot depend on residual LDS from a previous launch.
__global__ __launch_bounds__(512, 2)
void plrnn_mfma(const float* __restrict__ X, const float* __restrict__ A,
                const float* __restrict__ W1, const float* __restrict__ W2,
                const float* __restrict__ h1, const float* __restrict__ h2,
                float* __restrict__ out) {
    __shared__ uint32_t lds[LDS_DWORDS];
    uint16_t* zf_hi = (uint16_t*)lds;
    uint16_t* zf_lo = zf_hi + 2304;
    uint16_t* hd_hi = zf_hi + 4608;
    uint16_t* hd_lo = zf_hi + 8832;

    const int tid  = threadIdx.x;
    const int w    = tid >> 6;
    const int lane = tid & 63;
    const int n    = lane & 15;
    const int q    = lane >> 4;
    const int m2   = w & 3;
    const int bglob = (blockIdx.x << 4) | n;

    // ---- deterministic LDS state across launches ----
#pragma unroll
    for (int i = 0; i < 13; ++i) {
        int idx = tid + 512 * i;
        if (idx < LDS_DWORDS) lds[idx] = 0u;
    }

    // ---- persistent weight frags (A-operand: elem j -> A[m=lane&15][k=8q+j]) ----
    bf16x8 w2h[2][2], w2l[2][2];  // y = 32w+16tau+n, k = 32kf+8q
#pragma unroll
    for (int tau = 0; tau < 2; ++tau)
#pragma unroll
        for (int kf = 0; kf < 2; ++kf)
            split8(&W2[(32 * w + 16 * tau + n) * DZ + 32 * kf + 8 * q],
                   w2h[tau][kf], w2l[tau][kf]);
    bf16x8 w1h[8], w1l[8];        // z = 16*m2+n, k = 32*kfl+8q (full K=256)
#pragma unroll
    for (int kfl = 0; kfl < 8; ++kfl)
        split8(&W1[(16 * m2 + n) * DY + 32 * kfl + 8 * q], w1h[kfl], w1l[kfl]);

    float h2v[2][4];
#pragma unroll
    for (int tau = 0; tau < 2; ++tau)
#pragma unroll
        for (int i = 0; i < 4; ++i)
            h2v[tau][i] = h2[32 * w + 16 * tau + 4 * q + i];
    float Av[4], h1v[4], zf32[4];
#pragma unroll
    for (int i = 0; i < 4; ++i) {
        int z = 16 * m2 + 4 * q + i;
        Av[i] = A[z]; h1v[i] = h1[z]; zf32[i] = 0.0f;
    }

    const float* Xrow = X   + (size_t)bglob * TT * DX;
    float*       Orow = out + (size_t)bglob * TT * DX;

    __syncthreads();  // zero-init visible

    // ---- zf for t=0 (parity 0): tf(tf(0,x0,1), x0, .125) == x0 (non-NaN) ----
    if (w < 4) {
        float v[4];
#pragma unroll
        for (int i = 0; i < 4; ++i) {
            int z = 16 * w + 4 * q + i;
            float x0 = (z < DX) ? Xrow[z] : 0.0f;
            v[i] = (x0 == x0 && z < DX) ? x0 : 0.0f;
            zf32[i] = v[i];
        }
        int k0 = 16 * w + 4 * q;
        uint2 dh = make_uint2(pk_hi16(v[0], v[1]), pk_hi16(v[2], v[3]));
        float r0 = v[0] - trunc_bf16_f32(v[0]), r1 = v[1] - trunc_bf16_f32(v[1]);
        float r2 = v[2] - trunc_bf16_f32(v[2]), r3 = v[3] - trunc_bf16_f32(v[3]);
        uint2 dl = make_uint2(pk_hi16(r0, r1), pk_hi16(r2, r3));
        *(uint2*)&zf_hi[n * ZF_ROW + k0] = dh;
        *(uint2*)&zf_lo[n * ZF_ROW + k0] = dl;
    }
    __syncthreads();

    for (int t = 0; t < TT; ++t) {
        const int p  = (t & 1) * ZF_PAR;
        const int pn = ((t & 1) ^ 1) * ZF_PAR;

        // prefetch x(t+1) (waves 0,1 = output/TF rows)
        float4 xp = make_float4(0.f, 0.f, 0.f, 0.f);
        if (w < 2 && (t + 1) < TT)
            xp = *(const float4*)(Xrow + (t + 1) * DX + 16 * w + 4 * q);

        // ---- GEMM1: hidden = relu(W2 @ zf + h2) ----
        bf16x8 bh[2], bl[2];
#pragma unroll
        for (int kf = 0; kf < 2; ++kf) {
            bh[kf] = *(const bf16x8*)&zf_hi[p + n * ZF_ROW + 32 * kf + 8 * q];
            bl[kf] = *(const bf16x8*)&zf_lo[p + n * ZF_ROW + 32 * kf + 8 * q];
        }
        f32x4 acc0 = {h2v[0][0], h2v[0][1], h2v[0][2], h2v[0][3]};
        f32x4 acc1 = {h2v[1][0], h2v[1][1], h2v[1][2], h2v[1][3]};
#pragma unroll
        for (int kf = 0; kf < 2; ++kf) {
            acc0 = __builtin_amdgcn_mfma_f32_16x16x32_bf16(w2l[0][kf], bh[kf], acc0, 0, 0, 0);
            acc0 = __builtin_amdgcn_mfma_f32_16x16x32_bf16(w2h[0][kf], bl[kf], acc0, 0, 0, 0);
            acc0 = __builtin_amdgcn_mfma_f32_16x16x32_bf16(w2h[0][kf], bh[kf], acc0, 0, 0, 0);
            acc1 = __builtin_amdgcn_mfma_f32_16x16x32_bf16(w2l[1][kf], bh[kf], acc1, 0, 0, 0);
            acc1 = __builtin_amdgcn_mfma_f32_16x16x32_bf16(w2h[1][kf], bl[kf], acc1, 0, 0, 0);
            acc1 = __builtin_amdgcn_mfma_f32_16x16x32_bf16(w2h[1][kf], bh[kf], acc1, 0, 0, 0);
        }
#pragma unroll
        for (int tau = 0; tau < 2; ++tau) {
            f32x4 acc = tau ? acc1 : acc0;
            float v0 = fmaxf(acc[0], 0.f), v1 = fmaxf(acc[1], 0.f);
            float v2 = fmaxf(acc[2], 0.f), v3 = fmaxf(acc[3], 0.f);
            uint2 dh = make_uint2(pk_hi16(v0, v1), pk_hi16(v2, v3));
            float r0 = v0 - trunc_bf16_f32(v0), r1 = v1 - trunc_bf16_f32(v1);
            float r2 = v2 - trunc_bf16_f32(v2), r3 = v3 - trunc_bf16_f32(v3);
            uint2 dl = make_uint2(pk_hi16(r0, r1), pk_hi16(r2, r3));
            int y0 = 32 * w + 16 * tau + 4 * q;
            *(uint2*)&hd_hi[n * HD_ROW + y0] = dh;
            *(uint2*)&hd_lo[n * HD_ROW + y0] = dl;
        }
        __syncthreads();  // (A) hidden visible

        // ---- GEMM2 + update: waves 0-3, full K, no partial exchange ----
        if (w < 4) {
            f32x4 accA = {fmaf(Av[0], zf32[0], h1v[0]), fmaf(Av[1], zf32[1], h1v[1]),
                          fmaf(Av[2], zf32[2], h1v[2]), fmaf(Av[3], zf32[3], h1v[3])};
            f32x4 accB = {0.f, 0.f, 0.f, 0.f};
#pragma unroll
            for (int kfl = 0; kfl < 4; ++kfl) {
                int kbA = 32 * kfl + 8 * q;
                int kbB = 32 * (kfl + 4) + 8 * q;
                bf16x8 chA = *(const bf16x8*)&hd_hi[n * HD_ROW + kbA];
                bf16x8 clA = *(const bf16x8*)&hd_lo[n * HD_ROW + kbA];
                bf16x8 chB = *(const bf16x8*)&hd_hi[n * HD_ROW + kbB];
                bf16x8 clB = *(const bf16x8*)&hd_lo[n * HD_ROW + kbB];
                accA = __builtin_amdgcn_mfma_f32_16x16x32_bf16(w1l[kfl], chA, accA, 0, 0, 0);
                accB = __builtin_amdgcn_mfma_f32_16x16x32_bf16(w1l[kfl + 4], chB, accB, 0, 0, 0);
                accA = __builtin_amdgcn_mfma_f32_16x16x32_bf16(w1h[kfl], clA, accA, 0, 0, 0);
                accB = __builtin_amdgcn_mfma_f32_16x16x32_bf16(w1h[kfl + 4], clB, accB, 0, 0, 0);
                accA = __builtin_amdgcn_mfma_f32_16x16x32_bf16(w1h[kfl], chA, accA, 0, 0, 0);
                accB = __builtin_amdgcn_mfma_f32_16x16x32_bf16(w1h[kfl + 4], chB, accB, 0, 0, 0);
            }
            float zn[4], zfn[4];
#pragma unroll
            for (int i = 0; i < 4; ++i) zn[i] = accA[i] + accB[i];
            if (w < 2) {
                *(float4*)(Orow + t * DX + 16 * w + 4 * q) =
                    make_float4(zn[0], zn[1], zn[2], zn[3]);
                if (t + 1 < TT) {
                    float xv[4] = {xp.x, xp.y, xp.z, xp.w};
#pragma unroll
                    for (int i = 0; i < 4; ++i)
                        zfn[i] = (xv[i] == xv[i])
                                   ? fmaf(ALPHA, xv[i], (1.0f - ALPHA) * zn[i])
                                   : zn[i];
                } else {
#pragma unroll
                    for (int i = 0; i < 4; ++i) zfn[i] = zn[i];
                }
            } else {
#pragma unroll
                for (int i = 0; i < 4; ++i) zfn[i] = zn[i];
            }
#pragma unroll
            for (int i = 0; i < 4; ++i) zf32[i] = zfn[i];
            int k0 = 16 * w + 4 * q;
            uint2 dh = make_uint2(pk_hi16(zfn[0], zfn[1]), pk_hi16(zfn[2], zfn[3]));
            float r0 = zfn[0] - trunc_bf16_f32(zfn[0]), r1 = zfn[1] - trunc_bf16_f32(zfn[1]);
            float r2 = zfn[2] - trunc_bf16_f32(zfn[2]), r3 = zfn[3] - trunc_bf16_f32(zfn[3]);
            uint2 dl = make_uint2(pk_hi16(r0, r1), pk_hi16(r2, r3));
            *(uint2*)&zf_hi[pn + n * ZF_ROW + k0] = dh;
            *(uint2*)&zf_lo[pn + n * ZF_ROW + k0] = dl;
        }
        __syncthreads();  // (B) zf(t+1) visible; hd free for overwrite
    }
}

extern "C" void kernel_launch(void* const* d_in, const int* in_sizes, int n_in,
                              void* d_out, int out_size, void* d_ws, size_t ws_size,
                              hipStream_t stream) {
    const float* X  = (const float*)d_in[0];
    const float* A  = (const float*)d_in[1];
    const float* W1 = (const float*)d_in[2];
    const float* W2 = (const float*)d_in[3];
    const float* h1 = (const float*)d_in[4];
    const float* h2 = (const float*)d_in[5];
    float* out = (float*)d_out;

    plrnn_mfma<<<32, 512, 0, stream>>>(X, A, W1, W2, h1, h2, out);
}